// Round 1
// baseline (425.991 us; speedup 1.0000x reference)
//
#include <hip/hip_runtime.h>
#include <math.h>

#define Dk 64
#define Sk 8
#define Nk 16384
#define Bk 64
#define Hk 128

#define XSTR 68
#define TROWS 32
#define TILES_PER_BLOCK 8
#define CHUNK (TROWS*TILES_PER_BLOCK)   // 256 rows per block
#define BLOCKS_PER_B (Nk/CHUNK)         // 64

__device__ __forceinline__ float sum8(float v){
  v += __shfl_xor(v,1,64); v += __shfl_xor(v,2,64); v += __shfl_xor(v,4,64);
  return v;
}
__device__ __forceinline__ float max8(float v){
  v = fmaxf(v,__shfl_xor(v,1,64)); v = fmaxf(v,__shfl_xor(v,2,64)); v = fmaxf(v,__shfl_xor(v,4,64));
  return v;
}
__device__ __forceinline__ float wsum64(float v){
  #pragma unroll
  for (int m=1;m<64;m<<=1) v += __shfl_xor(v,m,64);
  return v;
}

// ---------------------------------------------------------------------------
// Per-iteration fused pass: LN(x) -> logits (x.q~) -> softmax -> attns out,
// accumulate U[b,s,j] = sum_n a[n,s]*xln[n,j] and den[b,s] = sum_n a[n,s]
// ---------------------------------------------------------------------------
__global__ __launch_bounds__(256) void iter_kernel(
    const float* __restrict__ inp,
    const float* __restrict__ ln_g, const float* __restrict__ ln_b,
    const float* __restrict__ qtbuf,      // [B,S,D], scale folded
    float* __restrict__ attns_out,        // [B,N,S]
    float* __restrict__ U,                // [B,S,D]
    float* __restrict__ den,              // [B,S]
    int iter)
{
  __shared__ float xln[TROWS*XSTR];
  __shared__ float qts[Sk*XSTR];
  __shared__ float as_[TROWS*Sk];
  __shared__ float gv[Dk], bv[Dk];

  const int t = threadIdx.x;
  const int b = blockIdx.y;
  const int chunk = blockIdx.x;

  {
    const int s0 = t >> 6, j = t & 63;
    qts[s0*XSTR + j]     = qtbuf[(b*Sk + s0)*Dk + j];
    qts[(s0+4)*XSTR + j] = qtbuf[(b*Sk + s0+4)*Dk + j];
    if (t < Dk){ gv[t] = ln_g[t]; bv[t] = ln_b[t]; }
  }

  const int r  = t >> 3;        // row within tile (staging + phase 1)
  const int sl = t & 7;         // slot (phase 1)
  const int j0 = (t & 7) * 8;   // staged column start
  const int s0 = t >> 6;        // phase-2 slot base (owns s0 and s0+4)
  const int jj = t & 63;        // phase-2 column

  float u0 = 0.f, u1 = 0.f, den_acc = 0.f;
  const size_t rowbase = (size_t)b*Nk + (size_t)chunk*CHUNK;

  for (int tile = 0; tile < TILES_PER_BLOCK; ++tile) {
    __syncthreads();   // protect xln/as_ from previous phase-2 readers

    // ---- stage + LN (thread stages exactly the 8 floats it normalizes) ----
    const float* src = inp + (rowbase + (size_t)tile*TROWS)*Dk + t*8;
    float4 A  = *(const float4*)src;
    float4 B4 = *(const float4*)(src+4);
    float s1 = A.x+A.y+A.z+A.w + B4.x+B4.y+B4.z+B4.w;
    float s2 = A.x*A.x+A.y*A.y+A.z*A.z+A.w*A.w
             + B4.x*B4.x+B4.y*B4.y+B4.z*B4.z+B4.w*B4.w;
    s1 = sum8(s1); s2 = sum8(s2);
    const float mean = s1*(1.f/64.f);
    const float var  = s2*(1.f/64.f) - mean*mean;
    const float rstd = rsqrtf(var + 1e-5f);
    float vv[8] = {A.x,A.y,A.z,A.w,B4.x,B4.y,B4.z,B4.w};
    #pragma unroll
    for (int i=0;i<8;++i) vv[i] = (vv[i]-mean)*rstd*gv[j0+i] + bv[j0+i];
    float* dst = &xln[r*XSTR + j0];
    *(float4*)dst     = make_float4(vv[0],vv[1],vv[2],vv[3]);
    *(float4*)(dst+4) = make_float4(vv[4],vv[5],vv[6],vv[7]);
    __syncthreads();

    // ---- phase 1: logits, softmax (8-lane groups), attns, a ----
    float logit = 0.f;
    #pragma unroll
    for (int j=0;j<Dk;j+=4){
      float4 xv = *(const float4*)&xln[r*XSTR+j];
      float4 qv = *(const float4*)&qts[sl*XSTR+j];
      logit += xv.x*qv.x + xv.y*qv.y + xv.z*qv.z + xv.w*qv.w;
    }
    const float mx = max8(logit);
    const float e  = __expf(logit - mx);
    const float es = sum8(e);
    const float attn = e / es;

    const size_t n = rowbase + (size_t)tile*TROWS + r;  // includes b*Nk
    const size_t oidx = n*Sk + sl;
    const float a3 = attn * (1.f/3.f);
    if (iter == 0) attns_out[oidx] = a3; else attns_out[oidx] += a3;

    const float a = attn + 1e-8f;
    den_acc += a;
    as_[r*Sk + sl] = a;
    __syncthreads();

    // ---- phase 2: U accumulation (register accumulators across tiles) ----
    #pragma unroll 8
    for (int rr=0; rr<TROWS; ++rr){
      const float xv = xln[rr*XSTR + jj];
      u0 += as_[rr*Sk + s0]     * xv;
      u1 += as_[rr*Sk + s0 + 4] * xv;
    }
  }

  atomicAdd(&U[(b*Sk + s0)*Dk   + jj], u0);
  atomicAdd(&U[(b*Sk + s0+4)*Dk + jj], u1);

  den_acc += __shfl_xor(den_acc, 8, 64);
  den_acc += __shfl_xor(den_acc, 16, 64);
  den_acc += __shfl_xor(den_acc, 32, 64);
  if ((t & 63) < 8) atomicAdd(&den[b*Sk + sl], den_acc);
}

// ---------------------------------------------------------------------------
// Per-(b,s) slot state kernel: init (mode 0) or GRU+LN+MLP update (mode 1),
// then q~ = scale * (LN_s(slots) @ Wq^T) @ Wk for the next iteration.
// One wave (64 threads) per block, d = threadIdx.x.
// ---------------------------------------------------------------------------
__global__ __launch_bounds__(64) void slot_kernel(
    const float* __restrict__ slots_init,
    const float* __restrict__ mu, const float* __restrict__ lsig,
    const float* __restrict__ ln_s_g, const float* __restrict__ ln_s_b,
    const float* __restrict__ ln_m_g, const float* __restrict__ ln_m_b,
    const float* __restrict__ Wq, const float* __restrict__ Wk, const float* __restrict__ Wv,
    const float* __restrict__ w_ih, const float* __restrict__ w_hh,
    const float* __restrict__ b_ih, const float* __restrict__ b_hh,
    const float* __restrict__ W1, const float* __restrict__ b1,
    const float* __restrict__ W2, const float* __restrict__ b2,
    float* __restrict__ slots, const float* __restrict__ U, const float* __restrict__ den,
    float* __restrict__ qtbuf, float* __restrict__ slots_out, int mode)
{
  __shared__ float sh[Hk];    // reused scratch (up to 128 floats)
  __shared__ float shh[Dk];
  const int d  = threadIdx.x;
  const int bs = blockIdx.x;

  float snew;
  if (mode == 0) {
    snew = mu[d] + expf(lsig[d]) * slots_init[bs*Dk + d];
  } else {
    // updates = (U @ Wv^T) / den
    const float dn = den[bs];
    sh[d] = U[bs*Dk + d];
    __syncthreads();
    float num = 0.f;
    #pragma unroll
    for (int j=0;j<Dk;j+=4){
      float4 w = *(const float4*)&Wv[d*Dk+j];
      num += sh[j]*w.x + sh[j+1]*w.y + sh[j+2]*w.z + sh[j+3]*w.w;
    }
    const float upd = num / dn;
    const float h = slots[bs*Dk + d];
    __syncthreads();
    sh[d] = upd; shh[d] = h;
    __syncthreads();

    // GRU (gate order r, z, n)
    float gi_r=b_ih[d], gi_z=b_ih[Dk+d], gi_n=b_ih[2*Dk+d];
    float gh_r=b_hh[d], gh_z=b_hh[Dk+d], gh_n=b_hh[2*Dk+d];
    #pragma unroll 4
    for (int j=0;j<Dk;j+=4){
      const float x0=sh[j],  x1=sh[j+1],  x2=sh[j+2],  x3=sh[j+3];
      const float h0=shh[j], h1=shh[j+1], h2=shh[j+2], h3=shh[j+3];
      float4 w;
      w = *(const float4*)&w_ih[d*Dk+j];        gi_r += x0*w.x+x1*w.y+x2*w.z+x3*w.w;
      w = *(const float4*)&w_ih[(Dk+d)*Dk+j];   gi_z += x0*w.x+x1*w.y+x2*w.z+x3*w.w;
      w = *(const float4*)&w_ih[(2*Dk+d)*Dk+j]; gi_n += x0*w.x+x1*w.y+x2*w.z+x3*w.w;
      w = *(const float4*)&w_hh[d*Dk+j];        gh_r += h0*w.x+h1*w.y+h2*w.z+h3*w.w;
      w = *(const float4*)&w_hh[(Dk+d)*Dk+j];   gh_z += h0*w.x+h1*w.y+h2*w.z+h3*w.w;
      w = *(const float4*)&w_hh[(2*Dk+d)*Dk+j]; gh_n += h0*w.x+h1*w.y+h2*w.z+h3*w.w;
    }
    const float rg = 1.f/(1.f+expf(-(gi_r+gh_r)));
    const float zg = 1.f/(1.f+expf(-(gi_z+gh_z)));
    const float ng = tanhf(gi_n + rg*gh_n);
    const float hn = (1.f-zg)*ng + zg*h;

    // LN_m
    const float m  = wsum64(hn)*(1.f/64.f);
    const float dv = hn - m;
    const float vr = wsum64(dv*dv)*(1.f/64.f);
    const float mv = dv*rsqrtf(vr+1e-5f)*ln_m_g[d] + ln_m_b[d];
    __syncthreads();
    sh[d] = mv;
    __syncthreads();

    // MLP: relu(mv @ W1^T + b1) @ W2^T + b2  (each thread owns hidden d, d+64)
    float h1a = b1[d], h2a = b1[Dk+d];
    #pragma unroll 4
    for (int j=0;j<Dk;j+=4){
      const float x0=sh[j], x1=sh[j+1], x2=sh[j+2], x3=sh[j+3];
      float4 w;
      w = *(const float4*)&W1[d*Dk+j];      h1a += x0*w.x+x1*w.y+x2*w.z+x3*w.w;
      w = *(const float4*)&W1[(Dk+d)*Dk+j]; h2a += x0*w.x+x1*w.y+x2*w.z+x3*w.w;
    }
    h1a = fmaxf(h1a, 0.f); h2a = fmaxf(h2a, 0.f);
    __syncthreads();
    sh[d] = h1a; sh[Dk+d] = h2a;
    __syncthreads();
    float o = b2[d];
    #pragma unroll 4
    for (int tt=0;tt<Hk;tt+=4){
      float4 w = *(const float4*)&W2[d*Hk+tt];
      o += sh[tt]*w.x + sh[tt+1]*w.y + sh[tt+2]*w.z + sh[tt+3]*w.w;
    }
    snew = hn + o;
  }

  slots[bs*Dk + d] = snew;
  if (slots_out) slots_out[bs*Dk + d] = snew;

  // q~ for next iteration: sn = LN_s(snew); q = sn@Wq^T; qt = scale * q@Wk
  const float m2  = wsum64(snew)*(1.f/64.f);
  const float dv2 = snew - m2;
  const float vr2 = wsum64(dv2*dv2)*(1.f/64.f);
  const float sn  = dv2*rsqrtf(vr2+1e-5f)*ln_s_g[d] + ln_s_b[d];
  __syncthreads();
  sh[d] = sn;
  __syncthreads();
  float q = 0.f;
  #pragma unroll
  for (int j=0;j<Dk;j+=4){
    float4 w = *(const float4*)&Wq[d*Dk+j];
    q += sh[j]*w.x + sh[j+1]*w.y + sh[j+2]*w.z + sh[j+3]*w.w;
  }
  __syncthreads();
  sh[d] = q;
  __syncthreads();
  float qt = 0.f;
  for (int dd=0; dd<Dk; ++dd) qt += sh[dd]*Wk[dd*Dk + d];
  qtbuf[bs*Dk + d] = qt * 0.125f;   // scale = D^-0.5
}

extern "C" void kernel_launch(void* const* d_in, const int* in_sizes, int n_in,
                              void* d_out, int out_size, void* d_ws, size_t ws_size,
                              hipStream_t stream)
{
  const float* inp     = (const float*)d_in[0];
  const float* sinit   = (const float*)d_in[1];
  const float* ln_in_g = (const float*)d_in[2];
  const float* ln_in_b = (const float*)d_in[3];
  const float* ln_s_g  = (const float*)d_in[4];
  const float* ln_s_b  = (const float*)d_in[5];
  const float* ln_m_g  = (const float*)d_in[6];
  const float* ln_m_b  = (const float*)d_in[7];
  const float* Wq      = (const float*)d_in[8];
  const float* Wk      = (const float*)d_in[9];
  const float* Wv      = (const float*)d_in[10];
  const float* w_ih    = (const float*)d_in[11];
  const float* w_hh    = (const float*)d_in[12];
  const float* b_ih    = (const float*)d_in[13];
  const float* b_hh    = (const float*)d_in[14];
  const float* W1      = (const float*)d_in[15];
  const float* b1      = (const float*)d_in[16];
  const float* W2      = (const float*)d_in[17];
  const float* b2      = (const float*)d_in[18];
  const float* mu      = (const float*)d_in[19];
  const float* lsig    = (const float*)d_in[20];

  float* out       = (float*)d_out;
  float* out_slots = out;                    // [B,S,D] = 32768 floats
  float* out_attns = out + Bk*Sk*Dk;         // [B,N,S]

  char* w = (char*)d_ws;
  float* slots = (float*)(w);                // 131072 B
  float* qtbuf = (float*)(w + 131072);       // 131072 B
  float* U     = (float*)(w + 262144);       // 131072 B
  float* den   = (float*)(w + 393216);       // 2048 B

  // init slots + q~ for iter 0
  slot_kernel<<<Bk*Sk, Dk, 0, stream>>>(sinit, mu, lsig, ln_s_g, ln_s_b, ln_m_g, ln_m_b,
      Wq, Wk, Wv, w_ih, w_hh, b_ih, b_hh, W1, b1, W2, b2,
      slots, U, den, qtbuf, nullptr, 0);

  for (int it = 0; it < 3; ++it) {
    hipMemsetAsync(U, 0, 131072 + 2048, stream);   // zero U and den
    iter_kernel<<<dim3(BLOCKS_PER_B, Bk), 256, 0, stream>>>(
        inp, ln_in_g, ln_in_b, qtbuf, out_attns, U, den, it);
    slot_kernel<<<Bk*Sk, Dk, 0, stream>>>(sinit, mu, lsig, ln_s_g, ln_s_b, ln_m_g, ln_m_b,
        Wq, Wk, Wv, w_ih, w_hh, b_ih, b_hh, W1, b1, W2, b2,
        slots, U, den, qtbuf, (it==2) ? out_slots : nullptr, 1);
  }
}

// Round 2
// 386.589 us; speedup vs baseline: 1.1019x; 1.1019x over previous
//
#include <hip/hip_runtime.h>
#include <math.h>

#define Dk 64
#define Sk 8
#define Nk 16384
#define Bk 64
#define Hk 128

#define XSTR 68
#define TROWS 32
#define TILES_PER_BLOCK 8
#define CHUNK (TROWS*TILES_PER_BLOCK)   // 256 rows per block
#define BLOCKS_PER_B (Nk/CHUNK)         // 64

__device__ __forceinline__ float sum8(float v){
  v += __shfl_xor(v,1,64); v += __shfl_xor(v,2,64); v += __shfl_xor(v,4,64);
  return v;
}
__device__ __forceinline__ float max8(float v){
  v = fmaxf(v,__shfl_xor(v,1,64)); v = fmaxf(v,__shfl_xor(v,2,64)); v = fmaxf(v,__shfl_xor(v,4,64));
  return v;
}
__device__ __forceinline__ float wsum64(float v){
  #pragma unroll
  for (int m=1;m<64;m<<=1) v += __shfl_xor(v,m,64);
  return v;
}
__device__ __forceinline__ unsigned short f2b(float f){   // f32 -> bf16 RNE
  unsigned u = __float_as_uint(f);
  unsigned r = (u + 0x7FFFu + ((u>>16)&1u)) >> 16;
  return (unsigned short)r;
}
__device__ __forceinline__ float b2f(unsigned short h){
  return __uint_as_float(((unsigned)h)<<16);
}

// ---------------------------------------------------------------------------
// Fused per-iteration pass.
// MODE 0 (iter 0): read f32 input, LayerNorm, write bf16 xln cache, compute.
// MODE 1 (iters 1,2): read bf16 xln cache (L3-resident), no LN, attns RMW.
// Computes logits = xln . q~, softmax over slots, accumulates attns/3 into
// d_out, and U[b,s,:] = sum_n a*xln[n,:], den[b,s] = sum_n a  via atomics.
// ---------------------------------------------------------------------------
template<int MODE>
__global__ __launch_bounds__(256) void iter_kernel(
    const float* __restrict__ inp,
    unsigned short* __restrict__ xbf,
    const float* __restrict__ ln_g, const float* __restrict__ ln_b,
    const float* __restrict__ qtbuf,      // [B,S,D], scale folded
    float* __restrict__ attns_out,        // [B,N,S]
    float* __restrict__ U,                // [B,S,D]
    float* __restrict__ den)              // [B,S]
{
  __shared__ float xln[TROWS*XSTR];
  __shared__ float qts[Sk*XSTR];
  __shared__ float as_[TROWS*Sk];
  __shared__ float gv[Dk], bv[Dk];

  const int t = threadIdx.x;
  const int b = blockIdx.y;
  const int chunk = blockIdx.x;

  {
    const int sq = t >> 6, j = t & 63;
    qts[sq*XSTR + j]     = qtbuf[(b*Sk + sq)*Dk + j];
    qts[(sq+4)*XSTR + j] = qtbuf[(b*Sk + sq+4)*Dk + j];
    if (MODE == 0 && t < Dk){ gv[t] = ln_g[t]; bv[t] = ln_b[t]; }
  }

  const int r  = t >> 3;        // row within tile (staging + phase 1)
  const int sl = t & 7;         // slot (phase 1)
  const int j0 = (t & 7) * 8;   // staged column start
  const int s0 = t >> 6;        // phase-2 slot base (owns s0 and s0+4)
  const int jj = t & 63;        // phase-2 column

  float u0 = 0.f, u1 = 0.f, den_acc = 0.f;
  const size_t rowbase = (size_t)b*Nk + (size_t)chunk*CHUNK;

  // ---- prefetch tile 0 ----
  float4 A, B4; uint4 P;
  if (MODE == 0){
    const float* src = inp + rowbase*Dk + t*8;
    A  = *(const float4*)src;
    B4 = *(const float4*)(src+4);
  } else {
    P = *(const uint4*)(xbf + rowbase*Dk + t*8);
  }

  for (int tile = 0; tile < TILES_PER_BLOCK; ++tile) {
    __syncthreads();   // protect xln/as_ from previous phase-2 readers

    // ---- issue next-tile prefetch + attns RMW read early ----
    float4 An, Bn; uint4 Pn;
    if (tile+1 < TILES_PER_BLOCK){
      const size_t off = (rowbase + (size_t)(tile+1)*TROWS)*Dk + t*8;
      if (MODE == 0){ An = *(const float4*)(inp+off); Bn = *(const float4*)(inp+off+4); }
      else          { Pn = *(const uint4*)(xbf+off); }
    }
    const size_t n = rowbase + (size_t)tile*TROWS + r;  // includes b*Nk
    const size_t oidx = n*Sk + sl;
    float aold = 0.f;
    if (MODE == 1) aold = attns_out[oidx];

    // ---- stage current tile into LDS (f32) ----
    float vv[8];
    if (MODE == 0){
      float s1 = A.x+A.y+A.z+A.w + B4.x+B4.y+B4.z+B4.w;
      float s2 = A.x*A.x+A.y*A.y+A.z*A.z+A.w*A.w
               + B4.x*B4.x+B4.y*B4.y+B4.z*B4.z+B4.w*B4.w;
      s1 = sum8(s1); s2 = sum8(s2);
      const float mean = s1*(1.f/64.f);
      const float var  = s2*(1.f/64.f) - mean*mean;
      const float rstd = rsqrtf(var + 1e-5f);
      float raw[8] = {A.x,A.y,A.z,A.w,B4.x,B4.y,B4.z,B4.w};
      #pragma unroll
      for (int i=0;i<8;++i) vv[i] = (raw[i]-mean)*rstd*gv[j0+i] + bv[j0+i];
      // write bf16 cache (coalesced 16B/lane)
      uint4 pk;
      pk.x = (unsigned)f2b(vv[0]) | ((unsigned)f2b(vv[1])<<16);
      pk.y = (unsigned)f2b(vv[2]) | ((unsigned)f2b(vv[3])<<16);
      pk.z = (unsigned)f2b(vv[4]) | ((unsigned)f2b(vv[5])<<16);
      pk.w = (unsigned)f2b(vv[6]) | ((unsigned)f2b(vv[7])<<16);
      *(uint4*)(xbf + (rowbase + (size_t)tile*TROWS)*Dk + t*8) = pk;
    } else {
      vv[0]=b2f((unsigned short)(P.x&0xFFFF)); vv[1]=b2f((unsigned short)(P.x>>16));
      vv[2]=b2f((unsigned short)(P.y&0xFFFF)); vv[3]=b2f((unsigned short)(P.y>>16));
      vv[4]=b2f((unsigned short)(P.z&0xFFFF)); vv[5]=b2f((unsigned short)(P.z>>16));
      vv[6]=b2f((unsigned short)(P.w&0xFFFF)); vv[7]=b2f((unsigned short)(P.w>>16));
    }
    float* dst = &xln[r*XSTR + j0];
    *(float4*)dst     = make_float4(vv[0],vv[1],vv[2],vv[3]);
    *(float4*)(dst+4) = make_float4(vv[4],vv[5],vv[6],vv[7]);
    __syncthreads();

    // ---- phase 1: logits, softmax (8-lane groups), attns, a ----
    float logit = 0.f;
    #pragma unroll
    for (int j=0;j<Dk;j+=4){
      float4 xv = *(const float4*)&xln[r*XSTR+j];
      float4 qv = *(const float4*)&qts[sl*XSTR+j];
      logit += xv.x*qv.x + xv.y*qv.y + xv.z*qv.z + xv.w*qv.w;
    }
    const float mx = max8(logit);
    const float e  = __expf(logit - mx);
    const float es = sum8(e);
    const float attn = e / es;

    attns_out[oidx] = aold + attn * (1.f/3.f);

    const float a = attn + 1e-8f;
    den_acc += a;
    as_[r*Sk + sl] = a;
    __syncthreads();

    // ---- phase 2: U accumulation (register accumulators across tiles) ----
    #pragma unroll 8
    for (int rr=0; rr<TROWS; ++rr){
      const float xv = xln[rr*XSTR + jj];
      u0 += as_[rr*Sk + s0]     * xv;
      u1 += as_[rr*Sk + s0 + 4] * xv;
    }

    if (tile+1 < TILES_PER_BLOCK){ A = An; B4 = Bn; P = Pn; }
  }

  atomicAdd(&U[(b*Sk + s0)*Dk   + jj], u0);
  atomicAdd(&U[(b*Sk + s0+4)*Dk + jj], u1);

  den_acc += __shfl_xor(den_acc, 8, 64);
  den_acc += __shfl_xor(den_acc, 16, 64);
  den_acc += __shfl_xor(den_acc, 32, 64);
  if ((t & 63) < 8) atomicAdd(&den[b*Sk + sl], den_acc);
}

// ---------------------------------------------------------------------------
// Per-(b,s) slot state kernel: init (mode 0) or GRU+LN+MLP update (mode 1),
// then q~ = scale * (LN_s(slots) @ Wq^T) @ Wk for the next iteration.
// Also zeroes U/den for the next iter_kernel (replaces memset nodes).
// ---------------------------------------------------------------------------
__global__ __launch_bounds__(64) void slot_kernel(
    const float* __restrict__ slots_init,
    const float* __restrict__ mu, const float* __restrict__ lsig,
    const float* __restrict__ ln_s_g, const float* __restrict__ ln_s_b,
    const float* __restrict__ ln_m_g, const float* __restrict__ ln_m_b,
    const float* __restrict__ Wq, const float* __restrict__ Wk, const float* __restrict__ Wv,
    const float* __restrict__ w_ih, const float* __restrict__ w_hh,
    const float* __restrict__ b_ih, const float* __restrict__ b_hh,
    const float* __restrict__ W1, const float* __restrict__ b1,
    const float* __restrict__ W2, const float* __restrict__ b2,
    float* __restrict__ slots, float* __restrict__ U, float* __restrict__ den,
    float* __restrict__ qtbuf, float* __restrict__ slots_out, int mode)
{
  __shared__ float sh[Hk];    // reused scratch (up to 128 floats)
  __shared__ float shh[Dk];
  const int d  = threadIdx.x;
  const int bs = blockIdx.x;

  float snew;
  if (mode == 0) {
    snew = mu[d] + expf(lsig[d]) * slots_init[bs*Dk + d];
    U[bs*Dk + d] = 0.f;
    if (d == 0) den[bs] = 0.f;
  } else {
    // updates = (U @ Wv^T) / den
    const float dn = den[bs];
    sh[d] = U[bs*Dk + d];
    __syncthreads();
    U[bs*Dk + d] = 0.f;            // reset for next iteration's atomics
    if (d == 0) den[bs] = 0.f;
    float num = 0.f;
    #pragma unroll
    for (int j=0;j<Dk;j+=4){
      float4 w = *(const float4*)&Wv[d*Dk+j];
      num += sh[j]*w.x + sh[j+1]*w.y + sh[j+2]*w.z + sh[j+3]*w.w;
    }
    const float upd = num / dn;
    const float h = slots[bs*Dk + d];
    __syncthreads();
    sh[d] = upd; shh[d] = h;
    __syncthreads();

    // GRU (gate order r, z, n)
    float gi_r=b_ih[d], gi_z=b_ih[Dk+d], gi_n=b_ih[2*Dk+d];
    float gh_r=b_hh[d], gh_z=b_hh[Dk+d], gh_n=b_hh[2*Dk+d];
    #pragma unroll 4
    for (int j=0;j<Dk;j+=4){
      const float x0=sh[j],  x1=sh[j+1],  x2=sh[j+2],  x3=sh[j+3];
      const float h0=shh[j], h1=shh[j+1], h2=shh[j+2], h3=shh[j+3];
      float4 w;
      w = *(const float4*)&w_ih[d*Dk+j];        gi_r += x0*w.x+x1*w.y+x2*w.z+x3*w.w;
      w = *(const float4*)&w_ih[(Dk+d)*Dk+j];   gi_z += x0*w.x+x1*w.y+x2*w.z+x3*w.w;
      w = *(const float4*)&w_ih[(2*Dk+d)*Dk+j]; gi_n += x0*w.x+x1*w.y+x2*w.z+x3*w.w;
      w = *(const float4*)&w_hh[d*Dk+j];        gh_r += h0*w.x+h1*w.y+h2*w.z+h3*w.w;
      w = *(const float4*)&w_hh[(Dk+d)*Dk+j];   gh_z += h0*w.x+h1*w.y+h2*w.z+h3*w.w;
      w = *(const float4*)&w_hh[(2*Dk+d)*Dk+j]; gh_n += h0*w.x+h1*w.y+h2*w.z+h3*w.w;
    }
    const float rg = 1.f/(1.f+expf(-(gi_r+gh_r)));
    const float zg = 1.f/(1.f+expf(-(gi_z+gh_z)));
    const float ng = tanhf(gi_n + rg*gh_n);
    const float hn = (1.f-zg)*ng + zg*h;

    // LN_m
    const float m  = wsum64(hn)*(1.f/64.f);
    const float dv = hn - m;
    const float vr = wsum64(dv*dv)*(1.f/64.f);
    const float mv = dv*rsqrtf(vr+1e-5f)*ln_m_g[d] + ln_m_b[d];
    __syncthreads();
    sh[d] = mv;
    __syncthreads();

    // MLP: relu(mv @ W1^T + b1) @ W2^T + b2  (each thread owns hidden d, d+64)
    float h1a = b1[d], h2a = b1[Dk+d];
    #pragma unroll 4
    for (int j=0;j<Dk;j+=4){
      const float x0=sh[j], x1=sh[j+1], x2=sh[j+2], x3=sh[j+3];
      float4 w;
      w = *(const float4*)&W1[d*Dk+j];      h1a += x0*w.x+x1*w.y+x2*w.z+x3*w.w;
      w = *(const float4*)&W1[(Dk+d)*Dk+j]; h2a += x0*w.x+x1*w.y+x2*w.z+x3*w.w;
    }
    h1a = fmaxf(h1a, 0.f); h2a = fmaxf(h2a, 0.f);
    __syncthreads();
    sh[d] = h1a; sh[Dk+d] = h2a;
    __syncthreads();
    float o = b2[d];
    #pragma unroll 4
    for (int tt=0;tt<Hk;tt+=4){
      float4 w = *(const float4*)&W2[d*Hk+tt];
      o += sh[tt]*w.x + sh[tt+1]*w.y + sh[tt+2]*w.z + sh[tt+3]*w.w;
    }
    snew = hn + o;
  }

  slots[bs*Dk + d] = snew;
  if (slots_out) slots_out[bs*Dk + d] = snew;

  // q~ for next iteration: sn = LN_s(snew); q = sn@Wq^T; qt = scale * q@Wk
  const float m2  = wsum64(snew)*(1.f/64.f);
  const float dv2 = snew - m2;
  const float vr2 = wsum64(dv2*dv2)*(1.f/64.f);
  const float sn  = dv2*rsqrtf(vr2+1e-5f)*ln_s_g[d] + ln_s_b[d];
  __syncthreads();
  sh[d] = sn;
  __syncthreads();
  float q = 0.f;
  #pragma unroll
  for (int j=0;j<Dk;j+=4){
    float4 w = *(const float4*)&Wq[d*Dk+j];
    q += sh[j]*w.x + sh[j+1]*w.y + sh[j+2]*w.z + sh[j+3]*w.w;
  }
  __syncthreads();
  sh[d] = q;
  __syncthreads();
  float qt = 0.f;
  for (int dd=0; dd<Dk; ++dd) qt += sh[dd]*Wk[dd*Dk + d];
  qtbuf[bs*Dk + d] = qt * 0.125f;   // scale = D^-0.5
}

extern "C" void kernel_launch(void* const* d_in, const int* in_sizes, int n_in,
                              void* d_out, int out_size, void* d_ws, size_t ws_size,
                              hipStream_t stream)
{
  const float* inp     = (const float*)d_in[0];
  const float* sinit   = (const float*)d_in[1];
  const float* ln_in_g = (const float*)d_in[2];
  const float* ln_in_b = (const float*)d_in[3];
  const float* ln_s_g  = (const float*)d_in[4];
  const float* ln_s_b  = (const float*)d_in[5];
  const float* ln_m_g  = (const float*)d_in[6];
  const float* ln_m_b  = (const float*)d_in[7];
  const float* Wq      = (const float*)d_in[8];
  const float* Wk      = (const float*)d_in[9];
  const float* Wv      = (const float*)d_in[10];
  const float* w_ih    = (const float*)d_in[11];
  const float* w_hh    = (const float*)d_in[12];
  const float* b_ih    = (const float*)d_in[13];
  const float* b_hh    = (const float*)d_in[14];
  const float* W1      = (const float*)d_in[15];
  const float* b1      = (const float*)d_in[16];
  const float* W2      = (const float*)d_in[17];
  const float* b2      = (const float*)d_in[18];
  const float* mu      = (const float*)d_in[19];
  const float* lsig    = (const float*)d_in[20];

  float* out       = (float*)d_out;
  float* out_slots = out;                    // [B,S,D] = 32768 floats
  float* out_attns = out + Bk*Sk*Dk;         // [B,N,S]

  char* w = (char*)d_ws;
  float* slots = (float*)(w);                        // 131072 B
  float* qtbuf = (float*)(w + 131072);               // 131072 B
  float* U     = (float*)(w + 262144);               // 131072 B
  float* den   = (float*)(w + 393216);               // 2048 B
  unsigned short* xbf = (unsigned short*)(w + 524288);  // 134217728 B bf16 LN(x) cache

  // init slots + q~ for iter 0 (also zeroes U/den)
  slot_kernel<<<Bk*Sk, Dk, 0, stream>>>(sinit, mu, lsig, ln_s_g, ln_s_b, ln_m_g, ln_m_b,
      Wq, Wk, Wv, w_ih, w_hh, b_ih, b_hh, W1, b1, W2, b2,
      slots, U, den, qtbuf, nullptr, 0);

  for (int it = 0; it < 3; ++it) {
    if (it == 0)
      iter_kernel<0><<<dim3(BLOCKS_PER_B, Bk), 256, 0, stream>>>(
          inp, xbf, ln_in_g, ln_in_b, qtbuf, out_attns, U, den);
    else
      iter_kernel<1><<<dim3(BLOCKS_PER_B, Bk), 256, 0, stream>>>(
          inp, xbf, ln_in_g, ln_in_b, qtbuf, out_attns, U, den);
    slot_kernel<<<Bk*Sk, Dk, 0, stream>>>(sinit, mu, lsig, ln_s_g, ln_s_b, ln_m_g, ln_m_b,
        Wq, Wk, Wv, w_ih, w_hh, b_ih, b_hh, W1, b1, W2, b2,
        slots, U, den, qtbuf, (it==2) ? out_slots : nullptr, 1);
  }
}

// Round 3
// 355.394 us; speedup vs baseline: 1.1986x; 1.0878x over previous
//
#include <hip/hip_runtime.h>
#include <math.h>

#define Dk 64
#define Sk 8
#define Nk 16384
#define Bk 64
#define Hk 128

typedef __attribute__((ext_vector_type(8))) short   bf16x8;
typedef __attribute__((ext_vector_type(4))) float   f32x4;
typedef __attribute__((ext_vector_type(2))) unsigned int u32x2;
typedef __attribute__((ext_vector_type(4))) unsigned int u32x4;

union FragU { u32x4 u; bf16x8 s; };

__device__ __forceinline__ unsigned short f2b(float f){   // f32 -> bf16 RNE
  unsigned u = __float_as_uint(f);
  unsigned r = (u + 0x7FFFu + ((u>>16)&1u)) >> 16;
  return (unsigned short)r;
}
__device__ __forceinline__ unsigned pk2(float a, float b){
  return (unsigned)f2b(a) | ((unsigned)f2b(b)<<16);
}
__device__ __forceinline__ bf16x8 mkfrag(unsigned a0,unsigned a1,unsigned a2,unsigned a3){
  FragU x; x.u = (u32x4){a0,a1,a2,a3}; return x.s;
}
__device__ __forceinline__ bf16x8 mkfrag2(u32x2 a, u32x2 b){
  FragU x; x.u = (u32x4){a.x,a.y,b.x,b.y}; return x.s;
}
__device__ __forceinline__ float wsum64(float v){
  #pragma unroll
  for (int m=1;m<64;m<<=1) v += __shfl_xor(v,m,64);
  return v;
}

#define MFMA16(a,b,c) __builtin_amdgcn_mfma_f32_16x16x32_bf16(a,b,c,0,0,0)
#define TRRD(dst, addr)          asm volatile("ds_read_b64_tr_b16 %0, %1"              : "=v"(dst) : "v"(addr) : "memory")
#define TRRD_O(dst, addr, OFF)   asm volatile("ds_read_b64_tr_b16 %0, %1 offset:" #OFF : "=v"(dst) : "v"(addr) : "memory")

// ---------------------------------------------------------------------------
// MFMA-based fused iteration pass. Per wave: 32-row windows, no __syncthreads.
// LDS per wave: X staged as 4 col-tiles [32 rows][16 cols] bf16 (2048 elems)
//               P (= attn+eps) as [32 rows][16 slots] bf16     (512 elems)
// logits: D[slot][row] = mfma(A=qt frags, B=X row frags)
// U:      D[slot][col] = mfma(A=P^T via tr-read, B=X cols via tr-read)
// ---------------------------------------------------------------------------
template<int MODE>
__global__ __launch_bounds__(256) void iter_kernel(
    const float* __restrict__ inp, unsigned short* __restrict__ xbf,
    const float* __restrict__ ln_g, const float* __restrict__ ln_b,
    const float* __restrict__ qtbuf,      // [B,S,D], scale folded, f32
    float* __restrict__ attns_out,        // [B,N,S]
    float* __restrict__ U,                // [B,S,D]
    float* __restrict__ den)              // [B,S]
{
  __shared__ unsigned short shmem[4*2560];
  const int t   = threadIdx.x;
  const int wid = t>>6, l = t&63;
  const int r16 = l&15, g = l>>4;
  unsigned short* sh = &shmem[wid*2560];
  const unsigned ldsb = (unsigned)(unsigned long long)(void*)sh;

  const int gw = blockIdx.x*4 + wid;    // global wave id, 8192 waves
  const int b  = gw>>7;                 // 128 waves per batch
  const int w0 = (gw&127)*4;            // 4 windows of 32 rows per wave

  // qt A-fragments (A[slot=r16][k-chunk]); slots 8-15 duplicate 0-7 (ignored)
  bf16x8 qf0, qf1;
  {
    const float* qp = qtbuf + (size_t)((b<<3) + (r16&7))*Dk + g*8;
    f32x4 a0 = *(const f32x4*)(qp);    f32x4 a1 = *(const f32x4*)(qp+4);
    f32x4 c0 = *(const f32x4*)(qp+32); f32x4 c1 = *(const f32x4*)(qp+36);
    qf0 = mkfrag(pk2(a0.x,a0.y),pk2(a0.z,a0.w),pk2(a1.x,a1.y),pk2(a1.z,a1.w));
    qf1 = mkfrag(pk2(c0.x,c0.y),pk2(c0.z,c0.w),pk2(c1.x,c1.y),pk2(c1.z,c1.w));
  }

  f32x4 uacc0={0.f,0.f,0.f,0.f}, uacc1={0.f,0.f,0.f,0.f};
  f32x4 uacc2={0.f,0.f,0.f,0.f}, uacc3={0.f,0.f,0.f,0.f};
  f32x4 dacc = {0.f,0.f,0.f,0.f};

  f32x4 gv0,gv1,gv2,gv3, bv0,bv1,bv2,bv3;
  if (MODE==0){
    const float* gp = ln_g + g*16; const float* bp = ln_b + g*16;
    gv0=*(const f32x4*)gp;     gv1=*(const f32x4*)(gp+4);
    gv2=*(const f32x4*)(gp+8); gv3=*(const f32x4*)(gp+12);
    bv0=*(const f32x4*)bp;     bv1=*(const f32x4*)(bp+4);
    bv2=*(const f32x4*)(bp+8); bv3=*(const f32x4*)(bp+12);
  }

  for (int w4=0; w4<4; ++w4){
    const int win = w0 + w4;
    const size_t rowwin = (size_t)b*Nk + (size_t)win*32;
    bf16x8 xf00, xf01, xf10, xf11;   // [rt][kt] B-frags for logits

    // ---- load + stage X ----
    #pragma unroll
    for (int rt=0; rt<2; ++rt){
      const size_t row = rowwin + (size_t)(rt*16 + r16);
      const int rloc = rt*16 + r16;
      if (MODE==0){
        const float* src = inp + row*Dk + g*16;
        f32x4 x0=*(const f32x4*)src,     x1=*(const f32x4*)(src+4);
        f32x4 x2=*(const f32x4*)(src+8), x3=*(const f32x4*)(src+12);
        float s1 = (x0.x+x0.y+x0.z+x0.w)+(x1.x+x1.y+x1.z+x1.w)
                 + (x2.x+x2.y+x2.z+x2.w)+(x3.x+x3.y+x3.z+x3.w);
        float s2 = x0.x*x0.x+x0.y*x0.y+x0.z*x0.z+x0.w*x0.w
                 + x1.x*x1.x+x1.y*x1.y+x1.z*x1.z+x1.w*x1.w
                 + x2.x*x2.x+x2.y*x2.y+x2.z*x2.z+x2.w*x2.w
                 + x3.x*x3.x+x3.y*x3.y+x3.z*x3.z+x3.w*x3.w;
        s1 += __shfl_xor(s1,16,64); s1 += __shfl_xor(s1,32,64);
        s2 += __shfl_xor(s2,16,64); s2 += __shfl_xor(s2,32,64);
        const float mean = s1*(1.f/64.f);
        const float rstd = rsqrtf(s2*(1.f/64.f) - mean*mean + 1e-5f);
        x0 = (x0-mean)*rstd*gv0 + bv0;  x1 = (x1-mean)*rstd*gv1 + bv1;
        x2 = (x2-mean)*rstd*gv2 + bv2;  x3 = (x3-mean)*rstd*gv3 + bv3;
        u32x4 lo = {pk2(x0.x,x0.y),pk2(x0.z,x0.w),pk2(x1.x,x1.y),pk2(x1.z,x1.w)};
        u32x4 hi = {pk2(x2.x,x2.y),pk2(x2.z,x2.w),pk2(x3.x,x3.y),pk2(x3.z,x3.w)};
        u32x4* dst = (u32x4*)(xbf + row*Dk + g*16);   // bf16 cache for iters 1,2
        dst[0] = lo; dst[1] = hi;
        const int eb = g*512 + rloc*16;               // ct = g (cols 16g..16g+15)
        *(u32x4*)&sh[eb]   = lo;
        *(u32x4*)&sh[eb+8] = hi;
      } else {
        const unsigned short* sp = xbf + row*Dk;
        FragU f0, f1;
        f0.u = *(const u32x4*)(sp + g*8);        // cols 8g..8g+7
        f1.u = *(const u32x4*)(sp + 32 + g*8);   // cols 32+8g..+7
        if (rt==0){ xf00=f0.s; xf01=f1.s; } else { xf10=f0.s; xf11=f1.s; }
        const int c0 = g*8, c1 = 32+g*8;
        *(u32x4*)&sh[(c0>>4)*512 + rloc*16 + (c0&15)] = f0.u;
        *(u32x4*)&sh[(c1>>4)*512 + rloc*16 + (c1&15)] = f1.u;
      }
    }
    if (MODE==0){
      // read B-frags back from LDS (implicit lgkmcnt by compiler)
      #pragma unroll
      for (int rt=0; rt<2; ++rt){
        const int rloc = rt*16 + r16;
        const int c0 = g*8, c1 = 32+g*8;
        FragU f0, f1;
        f0.u = *(const u32x4*)&sh[(c0>>4)*512 + rloc*16 + (c0&15)];
        f1.u = *(const u32x4*)&sh[(c1>>4)*512 + rloc*16 + (c1&15)];
        if (rt==0){ xf00=f0.s; xf01=f1.s; } else { xf10=f0.s; xf11=f1.s; }
      }
    }

    // ---- logits + softmax per 16-row tile ----
    #pragma unroll
    for (int rt=0; rt<2; ++rt){
      f32x4 c = {0.f,0.f,0.f,0.f};
      c = MFMA16(qf0, rt ? xf10 : xf00, c);
      c = MFMA16(qf1, rt ? xf11 : xf01, c);
      // c[j] = logit[slot 4g+j][row r16]  (valid for g<2)
      float mx = fmaxf(fmaxf(c.x,c.y), fmaxf(c.z,c.w));
      mx = fmaxf(mx, __shfl_xor(mx,16,64));
      f32x4 e;
      e.x = __expf(c.x-mx); e.y = __expf(c.y-mx);
      e.z = __expf(c.z-mx); e.w = __expf(c.w-mx);
      float es = e.x+e.y+e.z+e.w;
      es += __shfl_xor(es,16,64);
      const float inv = 1.f/es;
      f32x4 at = e*inv;
      const size_t row = rowwin + (size_t)(rt*16 + r16);
      if (l < 32){
        f32x4* ap = (f32x4*)(attns_out + row*Sk + g*4);
        f32x4 nv = at*(1.f/3.f);
        if (MODE) nv = nv + *ap;
        *ap = nv;
      }
      f32x4 a = at + 1e-8f;
      dacc = dacc + a;
      u32x2 pk = {pk2(a.x,a.y), pk2(a.z,a.w)};
      *(u32x2*)&sh[2048 + (rt*16+r16)*16 + g*4] = pk;   // P[row][slot 4g..]
    }

    // ---- U accumulation via transpose-read MFMA ----
    asm volatile("s_waitcnt lgkmcnt(0)" ::: "memory");  // drain X/P ds_writes
    u32x2 p0,p1, b00,b01,b10,b11,b20,b21,b30,b31;
    const unsigned pA = ldsb + 4096 + g*256 + r16*2;    // P tile, rows 8g+j, col r16
    TRRD  (p0, pA);
    TRRD_O(p1, pA, 128);
    const unsigned xA = ldsb + g*256 + r16*2;           // X ct tiles
    TRRD  (b00, xA);          TRRD_O(b01, xA, 128);
    TRRD_O(b10, xA, 1024);    TRRD_O(b11, xA, 1152);
    TRRD_O(b20, xA, 2048);    TRRD_O(b21, xA, 2176);
    TRRD_O(b30, xA, 3072);    TRRD_O(b31, xA, 3200);
    asm volatile("s_waitcnt lgkmcnt(0)" ::: "memory");
    __builtin_amdgcn_sched_barrier(0);
    const bf16x8 pf = mkfrag2(p0,p1);
    uacc0 = MFMA16(pf, mkfrag2(b00,b01), uacc0);
    uacc1 = MFMA16(pf, mkfrag2(b10,b11), uacc1);
    uacc2 = MFMA16(pf, mkfrag2(b20,b21), uacc2);
    uacc3 = MFMA16(pf, mkfrag2(b30,b31), uacc3);
  }

  // ---- epilogue: den butterfly + atomics ----
  float dd0=dacc.x, dd1=dacc.y, dd2=dacc.z, dd3=dacc.w;
  #pragma unroll
  for (int m=1;m<16;m<<=1){
    dd0 += __shfl_xor(dd0,m,64); dd1 += __shfl_xor(dd1,m,64);
    dd2 += __shfl_xor(dd2,m,64); dd3 += __shfl_xor(dd3,m,64);
  }
  if (l < 32){
    if (r16 == 0){
      atomicAdd(&den[b*Sk + g*4 + 0], dd0);
      atomicAdd(&den[b*Sk + g*4 + 1], dd1);
      atomicAdd(&den[b*Sk + g*4 + 2], dd2);
      atomicAdd(&den[b*Sk + g*4 + 3], dd3);
    }
    const size_t ub = (size_t)(b*Sk + g*4)*Dk + r16;
    atomicAdd(&U[ub + 0*Dk +  0], uacc0.x); atomicAdd(&U[ub + 1*Dk +  0], uacc0.y);
    atomicAdd(&U[ub + 2*Dk +  0], uacc0.z); atomicAdd(&U[ub + 3*Dk +  0], uacc0.w);
    atomicAdd(&U[ub + 0*Dk + 16], uacc1.x); atomicAdd(&U[ub + 1*Dk + 16], uacc1.y);
    atomicAdd(&U[ub + 2*Dk + 16], uacc1.z); atomicAdd(&U[ub + 3*Dk + 16], uacc1.w);
    atomicAdd(&U[ub + 0*Dk + 32], uacc2.x); atomicAdd(&U[ub + 1*Dk + 32], uacc2.y);
    atomicAdd(&U[ub + 2*Dk + 32], uacc2.z); atomicAdd(&U[ub + 3*Dk + 32], uacc2.w);
    atomicAdd(&U[ub + 0*Dk + 48], uacc3.x); atomicAdd(&U[ub + 1*Dk + 48], uacc3.y);
    atomicAdd(&U[ub + 2*Dk + 48], uacc3.z); atomicAdd(&U[ub + 3*Dk + 48], uacc3.w);
  }
}

// ---------------------------------------------------------------------------
// Per-(b,s) slot state kernel (unchanged, passing): init or GRU+LN+MLP update,
// then q~ = scale * (LN_s(slots) @ Wq^T) @ Wk. Zeroes U/den for next iter.
// ---------------------------------------------------------------------------
__global__ __launch_bounds__(64) void slot_kernel(
    const float* __restrict__ slots_init,
    const float* __restrict__ mu, const float* __restrict__ lsig,
    const float* __restrict__ ln_s_g, const float* __restrict__ ln_s_b,
    const float* __restrict__ ln_m_g, const float* __restrict__ ln_m_b,
    const float* __restrict__ Wq, const float* __restrict__ Wk, const float* __restrict__ Wv,
    const float* __restrict__ w_ih, const float* __restrict__ w_hh,
    const float* __restrict__ b_ih, const float* __restrict__ b_hh,
    const float* __restrict__ W1, const float* __restrict__ b1,
    const float* __restrict__ W2, const float* __restrict__ b2,
    float* __restrict__ slots, float* __restrict__ U, float* __restrict__ den,
    float* __restrict__ qtbuf, float* __restrict__ slots_out, int mode)
{
  __shared__ float sh[Hk];
  __shared__ float shh[Dk];
  const int d  = threadIdx.x;
  const int bs = blockIdx.x;

  float snew;
  if (mode == 0) {
    snew = mu[d] + expf(lsig[d]) * slots_init[bs*Dk + d];
    U[bs*Dk + d] = 0.f;
    if (d == 0) den[bs] = 0.f;
  } else {
    const float dn = den[bs];
    sh[d] = U[bs*Dk + d];
    __syncthreads();
    U[bs*Dk + d] = 0.f;
    if (d == 0) den[bs] = 0.f;
    float num = 0.f;
    #pragma unroll
    for (int j=0;j<Dk;j+=4){
      float4 w = *(const float4*)&Wv[d*Dk+j];
      num += sh[j]*w.x + sh[j+1]*w.y + sh[j+2]*w.z + sh[j+3]*w.w;
    }
    const float upd = num / dn;
    const float h = slots[bs*Dk + d];
    __syncthreads();
    sh[d] = upd; shh[d] = h;
    __syncthreads();

    float gi_r=b_ih[d], gi_z=b_ih[Dk+d], gi_n=b_ih[2*Dk+d];
    float gh_r=b_hh[d], gh_z=b_hh[Dk+d], gh_n=b_hh[2*Dk+d];
    #pragma unroll 4
    for (int j=0;j<Dk;j+=4){
      const float x0=sh[j],  x1=sh[j+1],  x2=sh[j+2],  x3=sh[j+3];
      const float h0=shh[j], h1=shh[j+1], h2=shh[j+2], h3=shh[j+3];
      float4 w;
      w = *(const float4*)&w_ih[d*Dk+j];        gi_r += x0*w.x+x1*w.y+x2*w.z+x3*w.w;
      w = *(const float4*)&w_ih[(Dk+d)*Dk+j];   gi_z += x0*w.x+x1*w.y+x2*w.z+x3*w.w;
      w = *(const float4*)&w_ih[(2*Dk+d)*Dk+j]; gi_n += x0*w.x+x1*w.y+x2*w.z+x3*w.w;
      w = *(const float4*)&w_hh[d*Dk+j];        gh_r += h0*w.x+h1*w.y+h2*w.z+h3*w.w;
      w = *(const float4*)&w_hh[(Dk+d)*Dk+j];   gh_z += h0*w.x+h1*w.y+h2*w.z+h3*w.w;
      w = *(const float4*)&w_hh[(2*Dk+d)*Dk+j]; gh_n += h0*w.x+h1*w.y+h2*w.z+h3*w.w;
    }
    const float rg = 1.f/(1.f+expf(-(gi_r+gh_r)));
    const float zg = 1.f/(1.f+expf(-(gi_z+gh_z)));
    const float ng = tanhf(gi_n + rg*gh_n);
    const float hn = (1.f-zg)*ng + zg*h;

    const float m  = wsum64(hn)*(1.f/64.f);
    const float dv = hn - m;
    const float vr = wsum64(dv*dv)*(1.f/64.f);
    const float mv = dv*rsqrtf(vr+1e-5f)*ln_m_g[d] + ln_m_b[d];
    __syncthreads();
    sh[d] = mv;
    __syncthreads();

    float h1a = b1[d], h2a = b1[Dk+d];
    #pragma unroll 4
    for (int j=0;j<Dk;j+=4){
      const float x0=sh[j], x1=sh[j+1], x2=sh[j+2], x3=sh[j+3];
      float4 w;
      w = *(const float4*)&W1[d*Dk+j];      h1a += x0*w.x+x1*w.y+x2*w.z+x3*w.w;
      w = *(const float4*)&W1[(Dk+d)*Dk+j]; h2a += x0*w.x+x1*w.y+x2*w.z+x3*w.w;
    }
    h1a = fmaxf(h1a, 0.f); h2a = fmaxf(h2a, 0.f);
    __syncthreads();
    sh[d] = h1a; sh[Dk+d] = h2a;
    __syncthreads();
    float o = b2[d];
    #pragma unroll 4
    for (int tt=0;tt<Hk;tt+=4){
      float4 w = *(const float4*)&W2[d*Hk+tt];
      o += sh[tt]*w.x + sh[tt+1]*w.y + sh[tt+2]*w.z + sh[tt+3]*w.w;
    }
    snew = hn + o;
  }

  slots[bs*Dk + d] = snew;
  if (slots_out) slots_out[bs*Dk + d] = snew;

  const float m2  = wsum64(snew)*(1.f/64.f);
  const float dv2 = snew - m2;
  const float vr2 = wsum64(dv2*dv2)*(1.f/64.f);
  const float sn  = dv2*rsqrtf(vr2+1e-5f)*ln_s_g[d] + ln_s_b[d];
  __syncthreads();
  sh[d] = sn;
  __syncthreads();
  float q = 0.f;
  #pragma unroll
  for (int j=0;j<Dk;j+=4){
    float4 w = *(const float4*)&Wq[d*Dk+j];
    q += sh[j]*w.x + sh[j+1]*w.y + sh[j+2]*w.z + sh[j+3]*w.w;
  }
  __syncthreads();
  sh[d] = q;
  __syncthreads();
  float qt = 0.f;
  for (int dd=0; dd<Dk; ++dd) qt += sh[dd]*Wk[dd*Dk + d];
  qtbuf[bs*Dk + d] = qt * 0.125f;   // scale = D^-0.5
}

extern "C" void kernel_launch(void* const* d_in, const int* in_sizes, int n_in,
                              void* d_out, int out_size, void* d_ws, size_t ws_size,
                              hipStream_t stream)
{
  const float* inp     = (const float*)d_in[0];
  const float* sinit   = (const float*)d_in[1];
  const float* ln_in_g = (const float*)d_in[2];
  const float* ln_in_b = (const float*)d_in[3];
  const float* ln_s_g  = (const float*)d_in[4];
  const float* ln_s_b  = (const float*)d_in[5];
  const float* ln_m_g  = (const float*)d_in[6];
  const float* ln_m_b  = (const float*)d_in[7];
  const float* Wq      = (const float*)d_in[8];
  const float* Wk      = (const float*)d_in[9];
  const float* Wv      = (const float*)d_in[10];
  const float* w_ih    = (const float*)d_in[11];
  const float* w_hh    = (const float*)d_in[12];
  const float* b_ih    = (const float*)d_in[13];
  const float* b_hh    = (const float*)d_in[14];
  const float* W1      = (const float*)d_in[15];
  const float* b1      = (const float*)d_in[16];
  const float* W2      = (const float*)d_in[17];
  const float* b2      = (const float*)d_in[18];
  const float* mu      = (const float*)d_in[19];
  const float* lsig    = (const float*)d_in[20];

  float* out       = (float*)d_out;
  float* out_slots = out;                    // [B,S,D]
  float* out_attns = out + Bk*Sk*Dk;         // [B,N,S]

  char* w = (char*)d_ws;
  float* slots = (float*)(w);
  float* qtbuf = (float*)(w + 131072);
  float* U     = (float*)(w + 262144);
  float* den   = (float*)(w + 393216);
  unsigned short* xbf = (unsigned short*)(w + 524288);  // 134 MB bf16 LN(x) cache

  slot_kernel<<<Bk*Sk, Dk, 0, stream>>>(sinit, mu, lsig, ln_s_g, ln_s_b, ln_m_g, ln_m_b,
      Wq, Wk, Wv, w_ih, w_hh, b_ih, b_hh, W1, b1, W2, b2,
      slots, U, den, qtbuf, nullptr, 0);

  for (int it = 0; it < 3; ++it) {
    if (it == 0)
      iter_kernel<0><<<2048, 256, 0, stream>>>(
          inp, xbf, ln_in_g, ln_in_b, qtbuf, out_attns, U, den);
    else
      iter_kernel<1><<<2048, 256, 0, stream>>>(
          inp, xbf, ln_in_g, ln_in_b, qtbuf, out_attns, U, den);
    slot_kernel<<<Bk*Sk, Dk, 0, stream>>>(sinit, mu, lsig, ln_s_g, ln_s_b, ln_m_g, ln_m_b,
        Wq, Wk, Wv, w_ih, w_hh, b_ih, b_hh, W1, b1, W2, b2,
        slots, U, den, qtbuf, (it==2) ? out_slots : nullptr, 1);
  }
}

// Round 4
// 235.516 us; speedup vs baseline: 1.8088x; 1.5090x over previous
//
#include <hip/hip_runtime.h>
#include <math.h>

#define Dk 64
#define Sk 8
#define Nk 16384
#define Bk 64
#define Hk 128

typedef __attribute__((ext_vector_type(8))) short   bf16x8;
typedef __attribute__((ext_vector_type(4))) float   f32x4;
typedef __attribute__((ext_vector_type(2))) unsigned int u32x2;
typedef __attribute__((ext_vector_type(4))) unsigned int u32x4;

union FragU { u32x4 u; bf16x8 s; };

__device__ __forceinline__ unsigned short f2b(float f){   // f32 -> bf16 RNE
  unsigned u = __float_as_uint(f);
  unsigned r = (u + 0x7FFFu + ((u>>16)&1u)) >> 16;
  return (unsigned short)r;
}
__device__ __forceinline__ unsigned pk2(float a, float b){
  return (unsigned)f2b(a) | ((unsigned)f2b(b)<<16);
}
__device__ __forceinline__ bf16x8 mkfrag(unsigned a0,unsigned a1,unsigned a2,unsigned a3){
  FragU x; x.u = (u32x4){a0,a1,a2,a3}; return x.s;
}
__device__ __forceinline__ bf16x8 mkfrag2(u32x2 a, u32x2 b){
  FragU x; x.u = (u32x4){a.x,a.y,b.x,b.y}; return x.s;
}
__device__ __forceinline__ float wsum64(float v){
  #pragma unroll
  for (int m=1;m<64;m<<=1) v += __shfl_xor(v,m,64);
  return v;
}

#define MFMA16(a,b,c) __builtin_amdgcn_mfma_f32_16x16x32_bf16(a,b,c,0,0,0)
#define TRRD(dst, addr)          asm volatile("ds_read_b64_tr_b16 %0, %1"              : "=v"(dst) : "v"(addr) : "memory")
#define TRRD_O(dst, addr, OFF)   asm volatile("ds_read_b64_tr_b16 %0, %1 offset:" #OFF : "=v"(dst) : "v"(addr) : "memory")

// ---------------------------------------------------------------------------
// MFMA fused iteration pass. Per wave: 4 windows of 32 rows, prefetched.
// LDS per wave (skewed): X col-tile ct at byte ct*1056 ([32 rows][16 cols]
// bf16, 32 B/row); P tile at byte 4224 ([32 rows][16 slots] bf16).
// No global atomics: per-block U/den partials via LDS combine.
// ---------------------------------------------------------------------------
template<int MODE>
__global__ __launch_bounds__(256,4) void iter_kernel(
    const float* __restrict__ inp, unsigned short* __restrict__ xbf,
    const float* __restrict__ ln_g, const float* __restrict__ ln_b,
    const float* __restrict__ qtbuf,      // [B,S,D], scale folded, f32
    float* __restrict__ attns_out,        // [B,N,S]
    float* __restrict__ Upart,            // [2048][8][64]
    float* __restrict__ denpart)          // [2048][8]
{
  __shared__ unsigned short shmem[4*2688];   // 4 waves * 5376 B
  __shared__ float ured[4][512];
  __shared__ float dred[4][8];

  const int t   = threadIdx.x;
  const int wid = t>>6, l = t&63;
  const int r16 = l&15, g = l>>4;
  unsigned short* sh = &shmem[wid*2688];
  const unsigned ldsb = (unsigned)(unsigned long long)(void*)sh;

  const int blk = blockIdx.x;
  const int gw  = blk*4 + wid;          // 8192 waves
  const int b   = gw>>7;                // 128 waves per batch
  const int w0  = (gw&127)*4;           // 4 windows of 32 rows per wave

  // qt A-fragments (A[slot=r16][k-chunk]); slots 8-15 duplicate 0-7
  bf16x8 qf0, qf1;
  {
    const float* qp = qtbuf + (size_t)((b<<3) + (r16&7))*Dk + g*8;
    f32x4 a0 = *(const f32x4*)(qp);    f32x4 a1 = *(const f32x4*)(qp+4);
    f32x4 c0 = *(const f32x4*)(qp+32); f32x4 c1 = *(const f32x4*)(qp+36);
    qf0 = mkfrag(pk2(a0.x,a0.y),pk2(a0.z,a0.w),pk2(a1.x,a1.y),pk2(a1.z,a1.w));
    qf1 = mkfrag(pk2(c0.x,c0.y),pk2(c0.z,c0.w),pk2(c1.x,c1.y),pk2(c1.z,c1.w));
  }

  f32x4 uacc0={0.f,0.f,0.f,0.f}, uacc1={0.f,0.f,0.f,0.f};
  f32x4 uacc2={0.f,0.f,0.f,0.f}, uacc3={0.f,0.f,0.f,0.f};
  f32x4 dacc = {0.f,0.f,0.f,0.f};

  f32x4 gv0,gv1,gv2,gv3, bv0,bv1,bv2,bv3;
  if (MODE==0){
    const float* gp = ln_g + g*16; const float* bp = ln_b + g*16;
    gv0=*(const f32x4*)gp;     gv1=*(const f32x4*)(gp+4);
    gv2=*(const f32x4*)(gp+8); gv3=*(const f32x4*)(gp+12);
    bv0=*(const f32x4*)bp;     bv1=*(const f32x4*)(bp+4);
    bv2=*(const f32x4*)(bp+8); bv3=*(const f32x4*)(bp+12);
  }

  // ---- prefetch window 0 ----
  f32x4 cx[2][4];          // MODE0: f32 input rows
  u32x4 cp[2][2];          // MODE1: bf16 cache rows
  f32x4 ca[2] = {{0.f,0.f,0.f,0.f},{0.f,0.f,0.f,0.f}};   // MODE1: attns old (cur)
  f32x4 na[2] = {{0.f,0.f,0.f,0.f},{0.f,0.f,0.f,0.f}};   // MODE1: attns old (next)
  {
    const size_t rw0 = (size_t)b*Nk + (size_t)w0*32;
    if (MODE==0){
      #pragma unroll
      for (int rt=0; rt<2; ++rt){
        const float* src = inp + (rw0 + rt*16 + r16)*Dk + g*16;
        cx[rt][0]=*(const f32x4*)src;     cx[rt][1]=*(const f32x4*)(src+4);
        cx[rt][2]=*(const f32x4*)(src+8); cx[rt][3]=*(const f32x4*)(src+12);
      }
    } else {
      #pragma unroll
      for (int rt=0; rt<2; ++rt){
        const unsigned short* sp = xbf + (rw0 + rt*16 + r16)*Dk;
        cp[rt][0] = *(const u32x4*)(sp + g*8);
        cp[rt][1] = *(const u32x4*)(sp + 32 + g*8);
        if (l<32) ca[rt] = *(const f32x4*)(attns_out + (rw0+rt*16+r16)*Sk + g*4);
      }
    }
  }

  for (int w4=0; w4<4; ++w4){
    const size_t rowwin = (size_t)b*Nk + (size_t)(w0+w4)*32;
    bf16x8 xf00, xf01, xf10, xf11;

    // ---- step A: consume cur, stage X into LDS (skewed tiles) ----
    if (MODE==0){
      #pragma unroll
      for (int rt=0; rt<2; ++rt){
        const int rloc = rt*16 + r16;
        const size_t row = rowwin + rloc;
        f32x4 x0=cx[rt][0], x1=cx[rt][1], x2=cx[rt][2], x3=cx[rt][3];
        float s1 = (x0.x+x0.y+x0.z+x0.w)+(x1.x+x1.y+x1.z+x1.w)
                 + (x2.x+x2.y+x2.z+x2.w)+(x3.x+x3.y+x3.z+x3.w);
        float s2 = x0.x*x0.x+x0.y*x0.y+x0.z*x0.z+x0.w*x0.w
                 + x1.x*x1.x+x1.y*x1.y+x1.z*x1.z+x1.w*x1.w
                 + x2.x*x2.x+x2.y*x2.y+x2.z*x2.z+x2.w*x2.w
                 + x3.x*x3.x+x3.y*x3.y+x3.z*x3.z+x3.w*x3.w;
        s1 += __shfl_xor(s1,16,64); s1 += __shfl_xor(s1,32,64);
        s2 += __shfl_xor(s2,16,64); s2 += __shfl_xor(s2,32,64);
        const float mean = s1*(1.f/64.f);
        const float rstd = rsqrtf(s2*(1.f/64.f) - mean*mean + 1e-5f);
        x0 = (x0-mean)*rstd*gv0 + bv0;  x1 = (x1-mean)*rstd*gv1 + bv1;
        x2 = (x2-mean)*rstd*gv2 + bv2;  x3 = (x3-mean)*rstd*gv3 + bv3;
        u32x4 lo = {pk2(x0.x,x0.y),pk2(x0.z,x0.w),pk2(x1.x,x1.y),pk2(x1.z,x1.w)};
        u32x4 hi = {pk2(x2.x,x2.y),pk2(x2.z,x2.w),pk2(x3.x,x3.y),pk2(x3.z,x3.w)};
        u32x4* dst = (u32x4*)(xbf + row*Dk + g*16);
        dst[0] = lo; dst[1] = hi;
        const int sb = g*528 + rloc*16;          // byte g*1056 + rloc*32
        *(u32x4*)&sh[sb]   = lo;
        *(u32x4*)&sh[sb+8] = hi;
      }
    } else {
      #pragma unroll
      for (int rt=0; rt<2; ++rt){
        const int rloc = rt*16 + r16;
        FragU f0, f1; f0.u = cp[rt][0]; f1.u = cp[rt][1];
        if (rt==0){ xf00=f0.s; xf01=f1.s; } else { xf10=f0.s; xf11=f1.s; }
        const int i0 = (g>>1)*528     + rloc*16 + (g&1)*8;
        const int i1 = ((g>>1)+2)*528 + rloc*16 + (g&1)*8;
        *(u32x4*)&sh[i0] = cp[rt][0];
        *(u32x4*)&sh[i1] = cp[rt][1];
      }
    }

    // ---- step B: prefetch next window ----
    if (w4 < 3){
      const size_t rwn = rowwin + 32;
      if (MODE==0){
        #pragma unroll
        for (int rt=0; rt<2; ++rt){
          const float* src = inp + (rwn + rt*16 + r16)*Dk + g*16;
          cx[rt][0]=*(const f32x4*)src;     cx[rt][1]=*(const f32x4*)(src+4);
          cx[rt][2]=*(const f32x4*)(src+8); cx[rt][3]=*(const f32x4*)(src+12);
        }
      } else {
        #pragma unroll
        for (int rt=0; rt<2; ++rt){
          const unsigned short* sp = xbf + (rwn + rt*16 + r16)*Dk;
          cp[rt][0] = *(const u32x4*)(sp + g*8);
          cp[rt][1] = *(const u32x4*)(sp + 32 + g*8);
          if (l<32) na[rt] = *(const f32x4*)(attns_out + (rwn+rt*16+r16)*Sk + g*4);
        }
      }
    }

    if (MODE==0){
      // read logit B-frags back from staged LDS
      #pragma unroll
      for (int rt=0; rt<2; ++rt){
        const int rloc = rt*16 + r16;
        const int i0 = (g>>1)*528     + rloc*16 + (g&1)*8;
        const int i1 = ((g>>1)+2)*528 + rloc*16 + (g&1)*8;
        FragU f0, f1;
        f0.u = *(const u32x4*)&sh[i0];
        f1.u = *(const u32x4*)&sh[i1];
        if (rt==0){ xf00=f0.s; xf01=f1.s; } else { xf10=f0.s; xf11=f1.s; }
      }
    }

    // ---- step C: logits + softmax + attns + P stage ----
    #pragma unroll
    for (int rt=0; rt<2; ++rt){
      f32x4 c = {0.f,0.f,0.f,0.f};
      c = MFMA16(qf0, rt ? xf10 : xf00, c);
      c = MFMA16(qf1, rt ? xf11 : xf01, c);
      float mx = fmaxf(fmaxf(c.x,c.y), fmaxf(c.z,c.w));
      mx = fmaxf(mx, __shfl_xor(mx,16,64));
      f32x4 e;
      e.x = __expf(c.x-mx); e.y = __expf(c.y-mx);
      e.z = __expf(c.z-mx); e.w = __expf(c.w-mx);
      float es = e.x+e.y+e.z+e.w;
      es += __shfl_xor(es,16,64);
      f32x4 at = e*(1.f/es);
      if (l < 32){
        f32x4 nv = at*(1.f/3.f);
        if (MODE) nv = nv + ca[rt];
        *(f32x4*)(attns_out + (rowwin + rt*16 + r16)*Sk + g*4) = nv;
      }
      f32x4 a = at + 1e-8f;
      dacc = dacc + a;
      u32x2 pk = {pk2(a.x,a.y), pk2(a.z,a.w)};
      *(u32x2*)&sh[2112 + (rt*16+r16)*16 + g*4] = pk;   // P tile @ byte 4224
    }

    // ---- step D: U accumulation via transpose-read MFMA ----
    asm volatile("s_waitcnt lgkmcnt(0)" ::: "memory");
    u32x2 p0,p1, b00,b01,b10,b11,b20,b21,b30,b31;
    const unsigned pA = ldsb + 4224 + g*256 + r16*2;
    TRRD  (p0, pA);
    TRRD_O(p1, pA, 128);
    const unsigned xA = ldsb + g*256 + r16*2;
    TRRD  (b00, xA);          TRRD_O(b01, xA, 128);
    TRRD_O(b10, xA, 1056);    TRRD_O(b11, xA, 1184);
    TRRD_O(b20, xA, 2112);    TRRD_O(b21, xA, 2240);
    TRRD_O(b30, xA, 3168);    TRRD_O(b31, xA, 3296);
    asm volatile("s_waitcnt lgkmcnt(0)" ::: "memory");
    __builtin_amdgcn_sched_barrier(0);
    const bf16x8 pf = mkfrag2(p0,p1);
    uacc0 = MFMA16(pf, mkfrag2(b00,b01), uacc0);
    uacc1 = MFMA16(pf, mkfrag2(b10,b11), uacc1);
    uacc2 = MFMA16(pf, mkfrag2(b20,b21), uacc2);
    uacc3 = MFMA16(pf, mkfrag2(b30,b31), uacc3);

    if (MODE==1){ ca[0]=na[0]; ca[1]=na[1]; }
  }

  // ---- epilogue: block-level combine, one plain store per block ----
  float dd0=dacc.x, dd1=dacc.y, dd2=dacc.z, dd3=dacc.w;
  #pragma unroll
  for (int m=1;m<16;m<<=1){
    dd0 += __shfl_xor(dd0,m,64); dd1 += __shfl_xor(dd1,m,64);
    dd2 += __shfl_xor(dd2,m,64); dd3 += __shfl_xor(dd3,m,64);
  }
  if (l < 32){
    #pragma unroll
    for (int j=0;j<4;++j){
      ured[wid][(g*4+j)*64 +  0 + r16] = uacc0[j];
      ured[wid][(g*4+j)*64 + 16 + r16] = uacc1[j];
      ured[wid][(g*4+j)*64 + 32 + r16] = uacc2[j];
      ured[wid][(g*4+j)*64 + 48 + r16] = uacc3[j];
    }
    if (r16 == 0){
      dred[wid][g*4+0]=dd0; dred[wid][g*4+1]=dd1;
      dred[wid][g*4+2]=dd2; dred[wid][g*4+3]=dd3;
    }
  }
  __syncthreads();
  #pragma unroll
  for (int e=t; e<512; e+=256){
    Upart[(size_t)blk*512 + e] = ured[0][e]+ured[1][e]+ured[2][e]+ured[3][e];
  }
  if (t < 8) denpart[blk*8 + t] = dred[0][t]+dred[1][t]+dred[2][t]+dred[3][t];
}

// ---------------------------------------------------------------------------
// Per-(b,s) slot state kernel: init (mode 0) or GRU+LN+MLP update (mode 1),
// summing the 32 per-block U/den partials, then q~ for the next iteration.
// ---------------------------------------------------------------------------
__global__ __launch_bounds__(64) void slot_kernel(
    const float* __restrict__ slots_init,
    const float* __restrict__ mu, const float* __restrict__ lsig,
    const float* __restrict__ ln_s_g, const float* __restrict__ ln_s_b,
    const float* __restrict__ ln_m_g, const float* __restrict__ ln_m_b,
    const float* __restrict__ Wq, const float* __restrict__ Wk, const float* __restrict__ Wv,
    const float* __restrict__ w_ih, const float* __restrict__ w_hh,
    const float* __restrict__ b_ih, const float* __restrict__ b_hh,
    const float* __restrict__ W1, const float* __restrict__ b1,
    const float* __restrict__ W2, const float* __restrict__ b2,
    float* __restrict__ slots, const float* __restrict__ Upart,
    const float* __restrict__ denpart,
    float* __restrict__ qtbuf, float* __restrict__ slots_out, int mode)
{
  __shared__ float sh[Hk];
  __shared__ float shh[Dk];
  const int d  = threadIdx.x;
  const int bs = blockIdx.x;

  float snew;
  if (mode == 0) {
    snew = mu[d] + expf(lsig[d]) * slots_init[bs*Dk + d];
  } else {
    // sum partials: U[d], den
    const int b8 = bs>>3, s = bs&7;
    const float* up = Upart + (size_t)(b8*32)*512 + s*64 + d;
    float uval = 0.f;
    #pragma unroll 8
    for (int k2=0;k2<32;++k2) uval += up[k2*512];
    float dp = (d<32) ? denpart[(b8*32+d)*8 + s] : 0.f;
    const float dn = wsum64(dp);

    sh[d] = uval;
    __syncthreads();
    float num = 0.f;
    #pragma unroll
    for (int j=0;j<Dk;j+=4){
      float4 w = *(const float4*)&Wv[d*Dk+j];
      num += sh[j]*w.x + sh[j+1]*w.y + sh[j+2]*w.z + sh[j+3]*w.w;
    }
    const float upd = num / dn;
    const float h = slots[bs*Dk + d];
    __syncthreads();
    sh[d] = upd; shh[d] = h;
    __syncthreads();

    float gi_r=b_ih[d], gi_z=b_ih[Dk+d], gi_n=b_ih[2*Dk+d];
    float gh_r=b_hh[d], gh_z=b_hh[Dk+d], gh_n=b_hh[2*Dk+d];
    #pragma unroll 4
    for (int j=0;j<Dk;j+=4){
      const float x0=sh[j],  x1=sh[j+1],  x2=sh[j+2],  x3=sh[j+3];
      const float h0=shh[j], h1=shh[j+1], h2=shh[j+2], h3=shh[j+3];
      float4 w;
      w = *(const float4*)&w_ih[d*Dk+j];        gi_r += x0*w.x+x1*w.y+x2*w.z+x3*w.w;
      w = *(const float4*)&w_ih[(Dk+d)*Dk+j];   gi_z += x0*w.x+x1*w.y+x2*w.z+x3*w.w;
      w = *(const float4*)&w_ih[(2*Dk+d)*Dk+j]; gi_n += x0*w.x+x1*w.y+x2*w.z+x3*w.w;
      w = *(const float4*)&w_hh[d*Dk+j];        gh_r += h0*w.x+h1*w.y+h2*w.z+h3*w.w;
      w = *(const float4*)&w_hh[(Dk+d)*Dk+j];   gh_z += h0*w.x+h1*w.y+h2*w.z+h3*w.w;
      w = *(const float4*)&w_hh[(2*Dk+d)*Dk+j]; gh_n += h0*w.x+h1*w.y+h2*w.z+h3*w.w;
    }
    const float rg = 1.f/(1.f+expf(-(gi_r+gh_r)));
    const float zg = 1.f/(1.f+expf(-(gi_z+gh_z)));
    const float ng = tanhf(gi_n + rg*gh_n);
    const float hn = (1.f-zg)*ng + zg*h;

    const float m  = wsum64(hn)*(1.f/64.f);
    const float dv = hn - m;
    const float vr = wsum64(dv*dv)*(1.f/64.f);
    const float mv = dv*rsqrtf(vr+1e-5f)*ln_m_g[d] + ln_m_b[d];
    __syncthreads();
    sh[d] = mv;
    __syncthreads();

    float h1a = b1[d], h2a = b1[Dk+d];
    #pragma unroll 4
    for (int j=0;j<Dk;j+=4){
      const float x0=sh[j], x1=sh[j+1], x2=sh[j+2], x3=sh[j+3];
      float4 w;
      w = *(const float4*)&W1[d*Dk+j];      h1a += x0*w.x+x1*w.y+x2*w.z+x3*w.w;
      w = *(const float4*)&W1[(Dk+d)*Dk+j]; h2a += x0*w.x+x1*w.y+x2*w.z+x3*w.w;
    }
    h1a = fmaxf(h1a, 0.f); h2a = fmaxf(h2a, 0.f);
    __syncthreads();
    sh[d] = h1a; sh[Dk+d] = h2a;
    __syncthreads();
    float o = b2[d];
    #pragma unroll 4
    for (int tt=0;tt<Hk;tt+=4){
      float4 w = *(const float4*)&W2[d*Hk+tt];
      o += sh[tt]*w.x + sh[tt+1]*w.y + sh[tt+2]*w.z + sh[tt+3]*w.w;
    }
    snew = hn + o;
  }

  slots[bs*Dk + d] = snew;
  if (slots_out) slots_out[bs*Dk + d] = snew;

  const float m2  = wsum64(snew)*(1.f/64.f);
  const float dv2 = snew - m2;
  const float vr2 = wsum64(dv2*dv2)*(1.f/64.f);
  const float sn  = dv2*rsqrtf(vr2+1e-5f)*ln_s_g[d] + ln_s_b[d];
  __syncthreads();
  sh[d] = sn;
  __syncthreads();
  float q = 0.f;
  #pragma unroll
  for (int j=0;j<Dk;j+=4){
    float4 w = *(const float4*)&Wq[d*Dk+j];
    q += sh[j]*w.x + sh[j+1]*w.y + sh[j+2]*w.z + sh[j+3]*w.w;
  }
  __syncthreads();
  sh[d] = q;
  __syncthreads();
  float qt = 0.f;
  for (int dd=0; dd<Dk; ++dd) qt += sh[dd]*Wk[dd*Dk + d];
  qtbuf[bs*Dk + d] = qt * 0.125f;   // scale = D^-0.5
}

extern "C" void kernel_launch(void* const* d_in, const int* in_sizes, int n_in,
                              void* d_out, int out_size, void* d_ws, size_t ws_size,
                              hipStream_t stream)
{
  const float* inp     = (const float*)d_in[0];
  const float* sinit   = (const float*)d_in[1];
  const float* ln_in_g = (const float*)d_in[2];
  const float* ln_in_b = (const float*)d_in[3];
  const float* ln_s_g  = (const float*)d_in[4];
  const float* ln_s_b  = (const float*)d_in[5];
  const float* ln_m_g  = (const float*)d_in[6];
  const float* ln_m_b  = (const float*)d_in[7];
  const float* Wq      = (const float*)d_in[8];
  const float* Wk      = (const float*)d_in[9];
  const float* Wv      = (const float*)d_in[10];
  const float* w_ih    = (const float*)d_in[11];
  const float* w_hh    = (const float*)d_in[12];
  const float* b_ih    = (const float*)d_in[13];
  const float* b_hh    = (const float*)d_in[14];
  const float* W1      = (const float*)d_in[15];
  const float* b1      = (const float*)d_in[16];
  const float* W2      = (const float*)d_in[17];
  const float* b2      = (const float*)d_in[18];
  const float* mu      = (const float*)d_in[19];
  const float* lsig    = (const float*)d_in[20];

  float* out       = (float*)d_out;
  float* out_slots = out;                    // [B,S,D]
  float* out_attns = out + Bk*Sk*Dk;         // [B,N,S]

  char* w = (char*)d_ws;
  float* slots   = (float*)(w);                        // 131072 B
  float* qtbuf   = (float*)(w + 131072);               // 131072 B
  float* Upart   = (float*)(w + 262144);               // 4194304 B
  float* denpart = (float*)(w + 4456448);              // 65536 B
  unsigned short* xbf = (unsigned short*)(w + 4521984);  // 134 MB bf16 LN(x) cache

  slot_kernel<<<Bk*Sk, Dk, 0, stream>>>(sinit, mu, lsig, ln_s_g, ln_s_b, ln_m_g, ln_m_b,
      Wq, Wk, Wv, w_ih, w_hh, b_ih, b_hh, W1, b1, W2, b2,
      slots, Upart, denpart, qtbuf, nullptr, 0);

  for (int it = 0; it < 3; ++it) {
    if (it == 0)
      iter_kernel<0><<<2048, 256, 0, stream>>>(
          inp, xbf, ln_in_g, ln_in_b, qtbuf, out_attns, Upart, denpart);
    else
      iter_kernel<1><<<2048, 256, 0, stream>>>(
          inp, xbf, ln_in_g, ln_in_b, qtbuf, out_attns, Upart, denpart);
    slot_kernel<<<Bk*Sk, Dk, 0, stream>>>(sinit, mu, lsig, ln_s_g, ln_s_b, ln_m_g, ln_m_b,
        Wq, Wk, Wv, w_ih, w_hh, b_ih, b_hh, W1, b1, W2, b2,
        slots, Upart, denpart, qtbuf, (it==2) ? out_slots : nullptr, 1);
  }
}